// Round 15
// baseline (12.295 us; speedup 1.0000x reference)
//
#include <hip/hip_runtime.h>

// GMP via MFMA: y[s] = sum_l (W[s-l,l] + a0[l]) * x[s-l], masked s<20.
// W[v,l] = sum_f Phi[v][f] * Theta[f][l]  (GEMM, K=64 padded)
//   Phi[v][4j+c] = q_{c+1}[v-j], j=0..10 valid    q_k = |x|^k
//   Theta[4*0+c][l] = a[c+1][9-l] (c<3), 0 for c=3
//   Theta[4(1+m)+c][l] = b[c][l][m], m=0..9;  f>=44 or l>=10 -> 0
//   bias a0[l] = a[0][9-l] added in the combine epilogue.
//
// Round-15: round-14 (TILE=256 latency A/B) with its crash fixed: the
// Q-build clamp lost the upper bound (p < S) in the r13->r14 edit, so
// the last blocks read past the end of x -> memory fault. Restored.
// Out-of-row positions produce zero quads feeding only unused wl slots.

typedef short short8 __attribute__((ext_vector_type(8)));
typedef float f32x4 __attribute__((ext_vector_type(4)));

constexpr int S_FIXED = 16384;
constexpr int BLK = 256;          // 4 waves
constexpr int TILE = 256;         // samples per block (64 per wave)
constexpr int GROUPS = 5;         // 16-position MFMA groups per wave
constexpr int IMAX = 79;          // reversed-table top index
constexpr int QRN = 96;           // qr entries per wave
constexpr int WLW = 84;           // wl row width (floats)

__device__ __forceinline__ unsigned short bfc(float f) {
    union { float f; unsigned u; } v; v.f = f;
    const unsigned u = v.u;
    return (unsigned short)((u + 0x7FFFu + ((u >> 16) & 1u)) >> 16);
}

__device__ __forceinline__ short8 mk8(ushort4 lo, ushort4 hi) {
    union { ushort4 u[2]; short8 s; } x;
    x.u[0] = lo; x.u[1] = hi;
    return x.s;
}

__global__ __launch_bounds__(BLK) void gmp_mfma(
    const float* __restrict__ x,   // (B, S, 2)
    const float* __restrict__ a,   // (4, 10)
    const float* __restrict__ b,   // (4, 10, 10)
    float* __restrict__ out,       // (B, S, 2)
    int S)
{
    __shared__ alignas(16) unsigned short th[16][64];   // Theta[col=l][f] bf16
    __shared__ alignas(16) ushort4 qr[4][QRN];          // per-wave reversed quads
    __shared__ alignas(16) float wl[4][10][WLW];        // per-wave W[l][pos-idx]

    const int t = threadIdx.x;
    const int wid = t >> 6, lane = t & 63;
    const int m = lane & 15, h = lane >> 4;
    const int blocksPerRow = S / TILE;                  // 64
    const int brow = blockIdx.x / blocksPerRow;
    const int s0   = (blockIdx.x % blocksPerRow) * TILE;
    const int s0w  = s0 + 64 * wid;                     // this wave's samples
    const int vb   = s0w - 12;                          // position base

    // ---- Theta build (block-wide, 1024 entries) ----
    for (int idx = t; idx < 1024; idx += BLK) {
        const int col = idx >> 6, f = idx & 63;
        float v = 0.f;
        if (col < 10 && f < 44) {            // j <= 10 only
            const int j = f >> 2, c = f & 3;
            if (j == 0) { if (c < 3) v = a[(c + 1) * 10 + (9 - col)]; }
            else v = b[c * 100 + col * 10 + (j - 1)];
        }
        th[col][f] = bfc(v);
    }

    // ---- Q build: reversed quad table, qr[wid][i] = quads(vb + IMAX - i) ----
    // out-of-row positions -> zero quads (hit only zero-Theta rows or
    // unused wl slots). BOTH bounds required (r14 crash: missing p < S).
    const float2* __restrict__ xr2 =
        reinterpret_cast<const float2*>(x) + (size_t)brow * S;
    for (int i = lane; i < QRN; i += 64) {
        const int p = vb + IMAX - i;
        float xre = 0.f, xim = 0.f;
        if (p >= 0 && p < S) { const float2 v = xr2[p]; xre = v.x; xim = v.y; }
        const float m2 = xre * xre + xim * xim;
        const float r  = __builtin_amdgcn_sqrtf(m2);
        ushort4 q;
        q.x = bfc(r); q.y = bfc(m2); q.z = bfc(m2 * r); q.w = bfc(m2 * m2);
        qr[wid][i] = q;
    }
    __syncthreads();   // th visible to all waves (qr is wave-private)

    // ---- B fragments (coefficients; once per wave) ----
    const short8 bfr0 = *reinterpret_cast<const short8*>(&th[m][8 * h]);
    const short8 bfr1 = *reinterpret_cast<const short8*>(&th[m][8 * h + 32]);

    // ---- MFMA: GROUPS groups of 16 positions; W -> LDS ----
    #pragma unroll
    for (int g = 0; g < GROUPS; ++g) {
        // A row m -> position p_m = vb + 16g + m; k chunk (h, frag F, pair e)
        // is feature j = 2h + e + 8F -> table idx IMAX - 16g - m + j.
        const int i1 = IMAX - 16 * g - m + 2 * h;
        const short8 af0 = mk8(qr[wid][i1],     qr[wid][i1 + 1]);
        const short8 af1 = mk8(qr[wid][i1 + 8], qr[wid][i1 + 9]);
        f32x4 acc = {0.f, 0.f, 0.f, 0.f};
        acc = __builtin_amdgcn_mfma_f32_16x16x32_bf16(af0, bfr0, acc, 0, 0, 0);
        acc = __builtin_amdgcn_mfma_f32_16x16x32_bf16(af1, bfr1, acc, 0, 0, 0);
        // D: col = lane&15 (= l), rows (lane>>4)*4 + r (= position offset)
        if (m < 10)
            *reinterpret_cast<f32x4*>(&wl[wid][m][16 * g + 4 * h]) = acc;
    }

    // ---- combine epilogue: 1 sample per lane ----
    const int sa0 = s0w + lane;
    float xre[10], xim[10];   // xre[i] = Re x[sa0 - 9 + i]
    #pragma unroll
    for (int i = 0; i < 10; ++i) {
        int p = sa0 - 9 + i;
        if (p < 0) p = 0;               // garbage -> masked s<20 only
        const float2 v = xr2[p];
        xre[i] = v.x; xim[i] = v.y;
    }
    float yr = 0.f, yi = 0.f;
    #pragma unroll
    for (int l = 0; l < 10; ++l) {
        const float w = wl[wid][l][lane + 12 - l] + a[9 - l];   // + a0[l]
        yr += w * xre[9 - l];
        yi += w * xim[9 - l];
    }
    const bool keep = sa0 >= 20;
    const float2 o = make_float2(keep ? yr : 0.f, keep ? yi : 0.f);
    reinterpret_cast<float2*>(out)[(size_t)brow * S + sa0] = o;
}

extern "C" void kernel_launch(void* const* d_in, const int* in_sizes, int n_in,
                              void* d_out, int out_size, void* d_ws, size_t ws_size,
                              hipStream_t stream) {
    const float* x = (const float*)d_in[0];
    const float* a = (const float*)d_in[1];
    const float* b = (const float*)d_in[2];
    // d_in[3] (c) is unused by the reference.
    float* out = (float*)d_out;

    const int S = S_FIXED;
    const int B = in_sizes[0] / (2 * S);
    const int nblocks = B * (S / TILE);

    gmp_mfma<<<dim3(nblocks), dim3(BLK), 0, stream>>>(x, a, b, out, S);
}

// Round 16
// 11.615 us; speedup vs baseline: 1.0585x; 1.0585x over previous
//
#include <hip/hip_runtime.h>

// GMP via MFMA: y[s] = sum_l (W[s-l,l] + a0[l]) * x[s-l], masked s<20.
// W[v,l] = sum_f Phi[v][f] * Theta[f][l]  (GEMM, K=64 padded)
//   Phi[v][4j+c] = q_{c+1}[v-j], j=0..10 valid    q_k = |x|^k
//   Theta[4*0+c][l] = a[c+1][9-l] (c<3), 0 for c=3
//   Theta[4(1+m)+c][l] = b[c][l][m], m=0..9;  f>=44 or l>=10 -> 0
//   bias a0[l] = a[0][9-l] added in the combine epilogue.
//
// Round-16: TILE=512 (r13 champion structure) with two throughput cuts:
//  (1) COALESCED Theta build: b via 100 float4 + a via 10 float4 +
//      146 8B zero-chunks (same th contents as r13's 440 gather loads);
//      th[col][3] zeroed by the a-loader threads.
//  (2) epilogue x-window (6 float4) + a0 biases hoisted right after the
//      barrier so their latency hides under the MFMA/DS groups.

typedef short short8 __attribute__((ext_vector_type(8)));
typedef float f32x4 __attribute__((ext_vector_type(4)));

constexpr int S_FIXED = 16384;
constexpr int BLK = 256;          // 4 waves
constexpr int TILE = 512;         // samples per block (128 per wave)
constexpr int GROUPS = 9;         // 16-position MFMA groups per wave
constexpr int IMAX = 143;         // reversed-table top index
constexpr int QRN = 160;          // qr entries per wave
constexpr int WLW = 148;          // wl row width (floats)

__device__ __forceinline__ unsigned short bfc(float f) {
    union { float f; unsigned u; } v; v.f = f;
    const unsigned u = v.u;
    return (unsigned short)((u + 0x7FFFu + ((u >> 16) & 1u)) >> 16);
}

__device__ __forceinline__ short8 mk8(ushort4 lo, ushort4 hi) {
    union { ushort4 u[2]; short8 s; } x;
    x.u[0] = lo; x.u[1] = hi;
    return x.s;
}

__global__ __launch_bounds__(BLK) void gmp_mfma(
    const float* __restrict__ x,   // (B, S, 2)
    const float* __restrict__ a,   // (4, 10)
    const float* __restrict__ b,   // (4, 10, 10)
    float* __restrict__ out,       // (B, S, 2)
    int S)
{
    __shared__ alignas(16) unsigned short th[16][64];   // Theta[col=l][f] bf16
    __shared__ alignas(16) ushort4 qr[4][QRN];          // per-wave reversed quads
    __shared__ alignas(16) float wl[4][10][WLW];        // per-wave W[l][pos-idx]

    const int t = threadIdx.x;
    const int wid = t >> 6, lane = t & 63;
    const int m = lane & 15, h = lane >> 4;
    const int blocksPerRow = S / TILE;                  // 32
    const int brow = blockIdx.x / blocksPerRow;
    const int s0   = (blockIdx.x % blocksPerRow) * TILE;
    const int s0w  = s0 + 128 * wid;                    // this wave's samples
    const int vb   = s0w - 12;                          // position base

    // ---- Theta build (coalesced; same contents as r13) ----
    if (t < 100) {                       // b: 400 floats = 100 float4
        const float4 bv = reinterpret_cast<const float4*>(b)[t];
        const float* bp = reinterpret_cast<const float*>(&bv);
        #pragma unroll
        for (int e = 0; e < 4; ++e) {
            const int i = 4 * t + e;     // = c*100 + l*10 + m
            const int c = i / 100, rem = i % 100;
            th[rem / 10][4 + 4 * (rem % 10) + c] = bfc(bp[e]);
        }
    } else if (t < 110) {                // a: 40 floats = 10 float4
        const int ct = t - 100;
        const float4 av = reinterpret_cast<const float4*>(a)[ct];
        const float* ap = reinterpret_cast<const float*>(&av);
        #pragma unroll
        for (int e = 0; e < 4; ++e) {
            const int i = 4 * ct + e;    // = k*10 + j
            const int k = i / 10, j = i % 10;
            if (k >= 1) th[9 - j][k - 1] = bfc(ap[e]);
        }
        th[ct][3] = 0;                   // Theta row f=3 is zero
    } else {                             // zero padding: 146 x 8B chunks
        const int z = t - 110;
        int col, off;
        if (z < 50) { col = z / 5;  off = 44 + (z % 5) * 4; }
        else { const int z2 = z - 50; col = 10 + (z2 >> 4); off = (z2 & 15) * 4; }
        ushort4 zz; zz.x = 0; zz.y = 0; zz.z = 0; zz.w = 0;
        *reinterpret_cast<ushort4*>(&th[col][off]) = zz;
    }

    // ---- Q build: reversed quad table, qr[wid][i] = quads(vb + IMAX - i) ----
    const float2* __restrict__ xr2 =
        reinterpret_cast<const float2*>(x) + (size_t)brow * S;
    for (int i = lane; i < QRN; i += 64) {
        const int p = vb + IMAX - i;
        float xre = 0.f, xim = 0.f;
        if (p >= 0 && p < S) { const float2 v = xr2[p]; xre = v.x; xim = v.y; }
        const float m2 = xre * xre + xim * xim;
        const float r  = __builtin_amdgcn_sqrtf(m2);
        ushort4 q;
        q.x = bfc(r); q.y = bfc(m2); q.z = bfc(m2 * r); q.w = bfc(m2 * m2);
        qr[wid][i] = q;
    }

    // a0 biases (uniform -> scalar loads; independent of LDS)
    float a0v[10];
    #pragma unroll
    for (int l = 0; l < 10; ++l) a0v[l] = a[9 - l];

    __syncthreads();   // th visible to all waves (qr is wave-private)

    // ---- epilogue x-window issued EARLY (hidden under MFMA groups) ----
    const int sa0 = s0w + 2 * lane;
    const float4* __restrict__ xr4 =
        reinterpret_cast<const float4*>(x) + (size_t)brow * (S / 2);
    float xf[24];   // complex window [sa0-10, sa0+2)
    {
        const int base4 = (sa0 - 10) / 2;   // sa0 even -> exact
        #pragma unroll
        for (int n = 0; n < 6; ++n) {
            int idx = base4 + n;
            if (idx < 0) idx = 0;           // garbage -> masked s<20 only
            const float4 f4 = xr4[idx];
            xf[4 * n + 0] = f4.x; xf[4 * n + 1] = f4.y;
            xf[4 * n + 2] = f4.z; xf[4 * n + 3] = f4.w;
        }
    }

    // ---- B fragments (coefficients; once per wave) ----
    const short8 bfr0 = *reinterpret_cast<const short8*>(&th[m][8 * h]);
    const short8 bfr1 = *reinterpret_cast<const short8*>(&th[m][8 * h + 32]);

    // ---- MFMA: GROUPS groups of 16 positions; W -> LDS ----
    #pragma unroll
    for (int g = 0; g < GROUPS; ++g) {
        const int i1 = IMAX - 16 * g - m + 2 * h;
        const short8 af0 = mk8(qr[wid][i1],     qr[wid][i1 + 1]);
        const short8 af1 = mk8(qr[wid][i1 + 8], qr[wid][i1 + 9]);
        f32x4 acc = {0.f, 0.f, 0.f, 0.f};
        acc = __builtin_amdgcn_mfma_f32_16x16x32_bf16(af0, bfr0, acc, 0, 0, 0);
        acc = __builtin_amdgcn_mfma_f32_16x16x32_bf16(af1, bfr1, acc, 0, 0, 0);
        // D: col = lane&15 (= l), rows (lane>>4)*4 + r (= position offset)
        if (m < 10)
            *reinterpret_cast<f32x4*>(&wl[wid][m][16 * g + 4 * h]) = acc;
    }

    // ---- combine epilogue: 2 samples per lane ----
    float yr0 = 0.f, yi0 = 0.f, yr1 = 0.f, yi1 = 0.f;
    #pragma unroll
    for (int l = 0; l < 10; ++l) {
        const float w0 = wl[wid][l][2 * lane + 12 - l] + a0v[l];
        const float w1 = wl[wid][l][2 * lane + 13 - l] + a0v[l];
        const int wp = 10 - l;                           // window pos, j=0
        yr0 += w0 * xf[2 * wp];     yi0 += w0 * xf[2 * wp + 1];
        yr1 += w1 * xf[2 * wp + 2]; yi1 += w1 * xf[2 * wp + 3];
    }
    const bool k0 = sa0 >= 20, k1 = (sa0 + 1) >= 20;
    const float4 o = make_float4(k0 ? yr0 : 0.f, k0 ? yi0 : 0.f,
                                 k1 ? yr1 : 0.f, k1 ? yi1 : 0.f);
    reinterpret_cast<float4*>(out)[((size_t)brow * S + sa0) / 2] = o;
}

extern "C" void kernel_launch(void* const* d_in, const int* in_sizes, int n_in,
                              void* d_out, int out_size, void* d_ws, size_t ws_size,
                              hipStream_t stream) {
    const float* x = (const float*)d_in[0];
    const float* a = (const float*)d_in[1];
    const float* b = (const float*)d_in[2];
    // d_in[3] (c) is unused by the reference.
    float* out = (float*)d_out;

    const int S = S_FIXED;
    const int B = in_sizes[0] / (2 * S);
    const int nblocks = B * (S / TILE);

    gmp_mfma<<<dim3(nblocks), dim3(BLK), 0, stream>>>(x, a, b, out, S);
}

// Round 17
// 11.113 us; speedup vs baseline: 1.1063x; 1.0452x over previous
//
#include <hip/hip_runtime.h>

// GMP via MFMA: y[s] = sum_l (W[s-l,l] + a0[l]) * x[s-l], masked s<20.
// W[v,l] = sum_f Phi[v][f] * Theta[f][l]  (GEMM, K=64 padded)
//   Phi[v][4j+c] = q_{c+1}[v-j], j=0..10 valid    q_k = |x|^k
//   Theta[4*0+c][l] = a[c+1][9-l] (c<3), 0 for c=3
//   Theta[4(1+m)+c][l] = b[c][l][m], m=0..9;  f>=44 or l>=10 -> 0
//   bias a0[l] = a[0][9-l] added in the combine epilogue.
//
// Round-17: r13 base (10.9us champion; r16's tweaks reverted) with two
// per-sample instruction cuts, numerics identical (RNE bf16):
//  (1) v_cvt_pk_bf16_f32 inline asm packs quad pairs: 2 inst vs 16.
//  (2) BLOCK-SHARED reversed quad table qs[544] (one build, not 4
//      overlapping per-wave tables: -15% entries), behind the existing
//      barrier. qs[i] = quads(s0 + 515 - i); wave reads at
//      i1 = 527 - 128*wid - 16g - m + 2h (j=0..15 span; j>=11 only
//      hits zero-Theta rows, same as r13).

typedef short short8 __attribute__((ext_vector_type(8)));
typedef float f32x4 __attribute__((ext_vector_type(4)));

constexpr int S_FIXED = 16384;
constexpr int BLK = 256;          // 4 waves
constexpr int TILE = 512;         // samples per block (128 per wave)
constexpr int GROUPS = 9;         // 16-position MFMA groups per wave
constexpr int QSN = 544;          // shared reversed-table entries
constexpr int WLW = 148;          // wl row width (floats)

__device__ __forceinline__ unsigned short bfc(float f) {
    union { float f; unsigned u; } v; v.f = f;
    const unsigned u = v.u;
    return (unsigned short)((u + 0x7FFFu + ((u >> 16) & 1u)) >> 16);
}

// RNE-pack two floats to packed bf16 pair (lo = s0, hi = s1).
__device__ __forceinline__ unsigned cvtpk(float lo, float hi) {
    unsigned r;
    asm("v_cvt_pk_bf16_f32 %0, %1, %2" : "=v"(r) : "v"(lo), "v"(hi));
    return r;
}

__device__ __forceinline__ short8 mk8(ushort4 lo, ushort4 hi) {
    union { ushort4 u[2]; short8 s; } x;
    x.u[0] = lo; x.u[1] = hi;
    return x.s;
}

__global__ __launch_bounds__(BLK) void gmp_mfma(
    const float* __restrict__ x,   // (B, S, 2)
    const float* __restrict__ a,   // (4, 10)
    const float* __restrict__ b,   // (4, 10, 10)
    float* __restrict__ out,       // (B, S, 2)
    int S)
{
    __shared__ alignas(16) unsigned short th[16][64];   // Theta[col=l][f] bf16
    __shared__ alignas(16) ushort4 qs[QSN];             // shared reversed quads
    __shared__ alignas(16) float wl[4][10][WLW];        // per-wave W[l][pos-idx]

    const int t = threadIdx.x;
    const int wid = t >> 6, lane = t & 63;
    const int m = lane & 15, h = lane >> 4;
    const int blocksPerRow = S / TILE;                  // 32
    const int brow = blockIdx.x / blocksPerRow;
    const int s0   = (blockIdx.x % blocksPerRow) * TILE;
    const int s0w  = s0 + 128 * wid;                    // this wave's samples

    // ---- Theta build (block-wide, 1024 entries; r13 form) ----
    for (int idx = t; idx < 1024; idx += BLK) {
        const int col = idx >> 6, f = idx & 63;
        float v = 0.f;
        if (col < 10 && f < 44) {            // j <= 10 only
            const int j = f >> 2, c = f & 3;
            if (j == 0) { if (c < 3) v = a[(c + 1) * 10 + (9 - col)]; }
            else v = b[c * 100 + col * 10 + (j - 1)];
        }
        th[col][f] = bfc(v);
    }

    // ---- shared Q build: qs[i] = quads(P), P = s0 + 515 - i ----
    const float2* __restrict__ xr2 =
        reinterpret_cast<const float2*>(x) + (size_t)brow * S;
    for (int i = t; i < QSN; i += BLK) {
        const int p = s0 + 515 - i;
        float xre = 0.f, xim = 0.f;
        if (p >= 0 && p < S) { const float2 v = xr2[p]; xre = v.x; xim = v.y; }
        const float m2 = xre * xre + xim * xim;
        const float r  = __builtin_amdgcn_sqrtf(m2);
        uint2 q;
        q.x = cvtpk(r, m2);            // bf16(q1) | bf16(q2)<<16
        q.y = cvtpk(m2 * r, m2 * m2);  // bf16(q3) | bf16(q4)<<16
        *reinterpret_cast<uint2*>(&qs[i]) = q;
    }
    __syncthreads();   // th + qs visible to all waves

    // ---- B fragments (coefficients; once per wave) ----
    const short8 bfr0 = *reinterpret_cast<const short8*>(&th[m][8 * h]);
    const short8 bfr1 = *reinterpret_cast<const short8*>(&th[m][8 * h + 32]);

    // ---- MFMA: GROUPS groups of 16 positions; W -> LDS ----
    const int ibase = 527 - 128 * wid;
    #pragma unroll
    for (int g = 0; g < GROUPS; ++g) {
        // A row m -> position p_m = s0w - 12 + 16g + m; feature j read at
        // qs[ibase - 16g - m + j], fragments j = {2h,2h+1} and {2h+8,2h+9}.
        const int i1 = ibase - 16 * g - m + 2 * h;
        const short8 af0 = mk8(qs[i1],     qs[i1 + 1]);
        const short8 af1 = mk8(qs[i1 + 8], qs[i1 + 9]);
        f32x4 acc = {0.f, 0.f, 0.f, 0.f};
        acc = __builtin_amdgcn_mfma_f32_16x16x32_bf16(af0, bfr0, acc, 0, 0, 0);
        acc = __builtin_amdgcn_mfma_f32_16x16x32_bf16(af1, bfr1, acc, 0, 0, 0);
        // D: col = lane&15 (= l), rows (lane>>4)*4 + r (= position offset)
        if (m < 10)
            *reinterpret_cast<f32x4*>(&wl[wid][m][16 * g + 4 * h]) = acc;
    }

    // ---- combine epilogue: 2 samples per lane (r13 form) ----
    const int sa0 = s0w + 2 * lane;
    const float4* __restrict__ xr4 =
        reinterpret_cast<const float4*>(x) + (size_t)brow * (S / 2);
    float xf[24];   // complex window [sa0-10, sa0+2)
    {
        const int base4 = (sa0 - 10) / 2;   // sa0 even -> exact
        #pragma unroll
        for (int n = 0; n < 6; ++n) {
            int idx = base4 + n;
            if (idx < 0) idx = 0;           // garbage -> masked s<20 only
            const float4 f4 = xr4[idx];
            xf[4 * n + 0] = f4.x; xf[4 * n + 1] = f4.y;
            xf[4 * n + 2] = f4.z; xf[4 * n + 3] = f4.w;
        }
    }
    float yr0 = 0.f, yi0 = 0.f, yr1 = 0.f, yi1 = 0.f;
    #pragma unroll
    for (int l = 0; l < 10; ++l) {
        const float bl = a[9 - l];                       // a[0][9-l]
        const float w0 = wl[wid][l][2 * lane + 12 - l] + bl;
        const float w1 = wl[wid][l][2 * lane + 13 - l] + bl;
        const int wp = 10 - l;                           // window pos, j=0
        yr0 += w0 * xf[2 * wp];     yi0 += w0 * xf[2 * wp + 1];
        yr1 += w1 * xf[2 * wp + 2]; yi1 += w1 * xf[2 * wp + 3];
    }
    const bool k0 = sa0 >= 20, k1 = (sa0 + 1) >= 20;
    const float4 o = make_float4(k0 ? yr0 : 0.f, k0 ? yi0 : 0.f,
                                 k1 ? yr1 : 0.f, k1 ? yi1 : 0.f);
    reinterpret_cast<float4*>(out)[((size_t)brow * S + sa0) / 2] = o;
}

extern "C" void kernel_launch(void* const* d_in, const int* in_sizes, int n_in,
                              void* d_out, int out_size, void* d_ws, size_t ws_size,
                              hipStream_t stream) {
    const float* x = (const float*)d_in[0];
    const float* a = (const float*)d_in[1];
    const float* b = (const float*)d_in[2];
    // d_in[3] (c) is unused by the reference.
    float* out = (float*)d_out;

    const int S = S_FIXED;
    const int B = in_sizes[0] / (2 * S);
    const int nblocks = B * (S / TILE);

    gmp_mfma<<<dim3(nblocks), dim3(BLK), 0, stream>>>(x, a, b, out, S);
}